// Round 1
// baseline (781.206 us; speedup 1.0000x reference)
//
#include <hip/hip_runtime.h>

#define HXc 64
#define HYc 64
#define Uc  512
#define Vc  512
#define Lc  16

__device__ __forceinline__ float4 ld4(const float* p) {
    return *reinterpret_cast<const float4*>(p);
}

__device__ __forceinline__ float4 bilerp(const float* __restrict__ base, int mm,
                                         float fi, float fj, int I, int J, int chan) {
    int i1 = (int)floorf(fi);
    int j1 = (int)floorf(fj);
    float ir = fi - (float)i1;
    float jr = fj - (float)j1;
    int i2 = (i1 + 1 == I) ? 0 : (i1 + 1);
    int j2 = (j1 + 1 == J) ? 0 : (j1 + 1);

    const float* p = base + (size_t)mm * I * J * Lc;
    int r1 = i1 * J;
    int r2 = i2 * J;

    float4 c11 = ld4(p + (r1 + j1) * Lc + chan);
    float4 c21 = ld4(p + (r2 + j1) * Lc + chan);
    float4 c12 = ld4(p + (r1 + j2) * Lc + chan);
    float4 c22 = ld4(p + (r2 + j2) * Lc + chan);

    float oir = 1.0f - ir;
    float ojr = 1.0f - jr;

    float4 res;
    res.x = (c11.x * oir + c21.x * ir) * ojr + (c12.x * oir + c22.x * ir) * jr;
    res.y = (c11.y * oir + c21.y * ir) * ojr + (c12.y * oir + c22.y * ir) * jr;
    res.z = (c11.z * oir + c21.z * ir) * ojr + (c12.z * oir + c22.z * ir) * jr;
    res.w = (c11.w * oir + c21.w * ir) * ojr + (c12.w * oir + c22.w * ir) * jr;
    return res;
}

__global__ __launch_bounds__(256) void triplane_kernel(
    const int*   __restrict__ m_arr,
    const float* __restrict__ h,
    const float* __restrict__ u_arr,
    const float* __restrict__ v_arr,
    const float* __restrict__ Fxy,
    const float* __restrict__ Fxu,
    const float* __restrict__ Fxv,
    const float* __restrict__ Fyu,
    const float* __restrict__ Fyv,
    const float* __restrict__ Fuv,
    float* __restrict__ out,
    int N)
{
    int tid = blockIdx.x * blockDim.x + threadIdx.x;
    int n   = tid >> 2;   // point index
    int sub = tid & 3;    // which float4 slice of the 16 channels
    if (n >= N) return;

    float h0 = h[2 * n];
    float h1 = h[2 * n + 1];
    float uu = u_arr[n];
    float vv = v_arr[n];
    int   mm = m_arr[n];

    float ind_hx = (h0 + 1.0f) / 2.0f * (float)HXc;
    float ind_hy = (h1 + 1.0f) / 2.0f * (float)HYc;
    if (ind_hx == (float)HXc) ind_hx = (float)(HXc - 1);
    if (ind_hy == (float)HYc) ind_hy = (float)(HYc - 1);
    float ind_u = uu * (float)Uc;
    float ind_v = vv * (float)Vc;
    if (ind_u == (float)Uc) ind_u = (float)(Uc - 1);
    if (ind_v == (float)Vc) ind_v = (float)(Vc - 1);

    int chan = sub * 4;

    float4 r0 = bilerp(Fxy, mm, ind_hx, ind_hy, HXc, HYc, chan);
    float4 r1 = bilerp(Fxu, mm, ind_hx, ind_u,  HXc, Uc,  chan);
    float4 r2 = bilerp(Fxv, mm, ind_hx, ind_v,  HXc, Vc,  chan);
    float4 r3 = bilerp(Fyu, mm, ind_hy, ind_u,  HYc, Uc,  chan);
    float4 r4 = bilerp(Fyv, mm, ind_hy, ind_v,  HYc, Vc,  chan);
    float4 r5 = bilerp(Fuv, mm, ind_u,  ind_v,  Uc,  Vc,  chan);

    float* o = out + (size_t)n * 96 + chan;
    *reinterpret_cast<float4*>(o + 0 * Lc) = r0;
    *reinterpret_cast<float4*>(o + 1 * Lc) = r1;
    *reinterpret_cast<float4*>(o + 2 * Lc) = r2;
    *reinterpret_cast<float4*>(o + 3 * Lc) = r3;
    *reinterpret_cast<float4*>(o + 4 * Lc) = r4;
    *reinterpret_cast<float4*>(o + 5 * Lc) = r5;
}

extern "C" void kernel_launch(void* const* d_in, const int* in_sizes, int n_in,
                              void* d_out, int out_size, void* d_ws, size_t ws_size,
                              hipStream_t stream) {
    // setup_inputs order: r(unused), m, h, u, v, Fxy, Fxu, Fxv, Fyu, Fyv, Fuv
    const int*   m_arr = (const int*)  d_in[1];
    const float* h     = (const float*)d_in[2];
    const float* u_arr = (const float*)d_in[3];
    const float* v_arr = (const float*)d_in[4];
    const float* Fxy   = (const float*)d_in[5];
    const float* Fxu   = (const float*)d_in[6];
    const float* Fxv   = (const float*)d_in[7];
    const float* Fyu   = (const float*)d_in[8];
    const float* Fyv   = (const float*)d_in[9];
    const float* Fuv   = (const float*)d_in[10];
    float* out = (float*)d_out;

    int N = in_sizes[0];
    int total_threads = 4 * N;
    dim3 block(256);
    dim3 grid((total_threads + 255) / 256);
    triplane_kernel<<<grid, block, 0, stream>>>(m_arr, h, u_arr, v_arr,
                                                Fxy, Fxu, Fxv, Fyu, Fyv, Fuv,
                                                out, N);
}